// Round 5
// baseline (174.759 us; speedup 1.0000x reference)
//
#include <hip/hip_runtime.h>

#define BB 4
#define CC 3
#define HH 512
#define WW 512
#define NS 81              // 9 x 9 shifts
#define IMG (HH * WW)
#define CHW (CC * IMG)
#define STRIP 16           // rows per k_sims block (R13 winner)
#define NSTRIPS (HH / STRIP)             // 32
#define NBLK (BB * CC * NSTRIPS)         // 384 blocks (ALL sx per block)
#define SLOTS (CC * NSTRIPS)             // 96 partials per (b, sim)

// R16: two findings drive this version.
//  (a) R14/R15 timed IDENTICALLY with totally different k_sims inner loops
//      (load-halo vs LDS-staged) -> inner loop is not the binding term; the
//      R13->R14 regression came from the outer changes (2x blocks, VGPR cap).
//      So k_sims reverts to the byte-identical R13 winner (95.8 us).
//  (b) Honest floors (k_sims ~4 us FMA-issue, k_apply ~6, k_reduce ~2) leave
//      ~30 us of the ~52 us non-fill time unexplained -> per-dispatch
//      overhead is the prime suspect. This version removes one dispatch:
//      k_reduce folds into k_sims via last-block-done (device-scope counter,
//      two-sided __threadfence, rocPRIM-proven pattern). Graph: 3 -> 2 nodes.
__device__ double g_part[(size_t)BB * NS * SLOTS];   // 249 KB, fully rewritten each launch
__device__ int    g_best[BB];
__device__ unsigned g_cnt = 0;   // completion counter; reset by the last block

// constant-index component select (folds after full unroll)
#define C4(v, i) ((i) == 0 ? (v).x : (i) == 1 ? (v).y : (i) == 2 ? (v).z : (v).w)

// sim(b,sx,sy) = sum over c,i,j (both (i,j) and (i+sx,j+sy) in bounds) of
//               x[b,c,i,j] * x_ref[b,c,i+sx,j+sy]
__global__ __launch_bounds__(576) void k_sims(const float* __restrict__ xref,
                                              const float* __restrict__ x,
                                              float* __restrict__ outTail) {
    int bid   = blockIdx.x;
    int strip = bid % NSTRIPS;
    int bc    = bid / NSTRIPS;
    int b     = bc / CC;
    const float* xp = x    + (size_t)bc * IMG;
    const float* rp = xref + (size_t)bc * IMG;
    int tid  = threadIdx.x;
    int lane = tid & 63;
    int sxi  = tid >> 6;                 // wave index == sx index (9 waves)
    int j0   = lane << 3;                // 8 floats per lane
    int sx   = sxi - 4;
    int ip0  = strip * STRIP;

    float acc[9];
#pragma unroll
    for (int s = 0; s < 9; ++s) acc[s] = 0.f;

#pragma unroll
    for (int rr = 0; rr < STRIP; ++rr) {
        int ip = ip0 + rr;               // x row (always in bounds)
        int ii = ip + sx;                // ref row (wave-uniform test)
        if ((unsigned)ii >= HH) continue;

        const float* xrow = xp + ip * WW + j0;
        const float* rrow = rp + ii * WW + j0;
        float4 xa = *(const float4*)(xrow);        // x   cols j0   .. j0+3
        float4 xb = *(const float4*)(xrow + 4);    // x   cols j0+4 .. j0+7
        float4 ra = *(const float4*)(rrow);        // ref cols j0   .. j0+3
        float4 rb = *(const float4*)(rrow + 4);    // ref cols j0+4 .. j0+7

        // halo: prev4 = ref cols j0-4..j0-1 (lane-1's rb), next4 = j0+8..j0+11
        float p0 = __shfl_up(rb.x, 1, 64);
        float p1 = __shfl_up(rb.y, 1, 64);
        float p2 = __shfl_up(rb.z, 1, 64);
        float p3 = __shfl_up(rb.w, 1, 64);
        if (lane == 0) { p0 = p1 = p2 = p3 = 0.f; }   // cols < 0 -> mask
        float n0 = __shfl_down(ra.x, 1, 64);
        float n1 = __shfl_down(ra.y, 1, 64);
        float n2 = __shfl_down(ra.z, 1, 64);
        float n3 = __shfl_down(ra.w, 1, 64);
        if (lane == 63) { n0 = n1 = n2 = n3 = 0.f; }  // cols >= 512 -> mask

#define P4(i) ((i) == 0 ? p0 : (i) == 1 ? p1 : (i) == 2 ? p2 : p3)
#define N4(i) ((i) == 0 ? n0 : (i) == 1 ? n1 : (i) == 2 ? n2 : n3)
#pragma unroll
        for (int syi = 0; syi < 9; ++syi) {
#pragma unroll
            for (int k = 0; k < 8; ++k) {
                int i = k + syi;         // window index 0..15 (constant)
                float wv = (i < 4)  ? P4(i)
                         : (i < 8)  ? C4(ra, i - 4)
                         : (i < 12) ? C4(rb, i - 8)
                         :            N4(i - 12);
                float xv = (k < 4) ? C4(xa, k) : C4(xb, k - 4);
                acc[syi] += xv * wv;
            }
        }
#undef P4
#undef N4
    }

    // Each wave owns 9 disjoint sims (its sx) -> no LDS combine, no atomics.
    // Wave shuffle-reduce (fp32, R13-identical), lane 0 stores fp64 partial.
    int cs = (bc % CC) * NSTRIPS + strip;            // partial slot 0..95
#pragma unroll
    for (int s = 0; s < 9; ++s) {
        float v = acc[s];
        for (int off = 32; off; off >>= 1) v += __shfl_down(v, off, 64);
        if (lane == 0)
            g_part[((size_t)b * NS + sxi * 9 + s) * SLOTS + cs] = (double)v;
    }

    // ---- last-block-done: the old k_reduce, without its dispatch ----
    // Release: every thread fences its own g_part stores (device scope),
    // then block syncs, then one atomic bump. Acquire: last block fences
    // before reading. Conservative two-sided pattern (G16 / rocPRIM-style).
    __shared__ unsigned isLast;
    __threadfence();
    __syncthreads();
    if (tid == 0) isLast = (atomicAdd(&g_cnt, 1u) == NBLK - 1) ? 1u : 0u;
    __syncthreads();
    if (!isLast) return;
    __threadfence();

    // Thread t sums (b,sim)=t's 96 fp64 partials in the SAME sequential
    // order as R13's k_reduce -> bit-identical totals, then per-batch
    // first-index argmax (strict >, matches jnp.argmax).
    __shared__ double vals[BB * NS];     // 2592 B
    if (tid < BB * NS) {
        const double* p = g_part + (size_t)tid * SLOTS;
        double s = 0.0;
        for (int i = 0; i < SLOTS; ++i) s += p[i];
        vals[tid] = s;
    }
    __syncthreads();
    if (tid < BB) {
        const double* v = vals + tid * NS;
        int best = 0;
        double bv = v[0];
        for (int i = 1; i < NS; ++i)
            if (v[i] > bv) { bv = v[i]; best = i; }   // strict >: first index wins
        g_best[tid] = best;
        outTail[tid * 2]     = (float)(best / 9 - 4);
        outTail[tid * 2 + 1] = (float)(best % 9 - 4);
        if (tid == 0) g_cnt = 0;         // self-reset for the next graph replay
    }
}

// Pure shift-copy: reads precomputed g_best[b] (wave-uniform scalar load).
// Copy body unchanged from R11-R15 (proven exact).
__global__ __launch_bounds__(256) void k_apply(const float* __restrict__ x,
                                               float* __restrict__ out) {
    int blk = blockIdx.x;
    int bc  = blk >> 8;                 // 256 blocks per image (512 rows / 2)
    int tid = threadIdx.x;
    int b   = bc / CC;

    int bi = g_best[b];
    int sx = bi / 9 - 4;
    int sy = bi % 9 - 4;

    int row = ((blk & 255) << 1) + (tid >> 7);
    int j0  = (tid & 127) << 2;
    int is  = row - sx;
    float4 v = make_float4(0.f, 0.f, 0.f, 0.f);
    if ((unsigned)is < HH) {
        const float* src = x + (size_t)bc * IMG + is * WW;
        int js0 = j0 - sy;
        if (js0 >= 0 && js0 + 3 < WW) {
            v = *(const float4*)(src + js0);   // 4B-aligned dwordx4, exact (R2-R16)
        } else {
            float* vv = (float*)&v;
#pragma unroll
            for (int k = 0; k < 4; ++k) {
                int js = js0 + k;
                if ((unsigned)js < WW) vv[k] = src[js];
            }
        }
    }
    *(float4*)(out + (size_t)bc * IMG + row * WW + j0) = v;
}

extern "C" void kernel_launch(void* const* d_in, const int* in_sizes, int n_in,
                              void* d_out, int out_size, void* d_ws, size_t ws_size,
                              hipStream_t stream) {
    const float* xref = (const float*)d_in[0];
    const float* x    = (const float*)d_in[1];
    float* out = (float*)d_out;
    (void)d_ws; (void)ws_size;          // workspace unused (poison fill is unconditional)

    k_sims<<<NBLK, 576, 0, stream>>>(xref, x, out + (size_t)BB * CHW);

    int applyBlocks = (BB * CC * HH) / 2;   // 3072
    k_apply<<<applyBlocks, 256, 0, stream>>>(x, out);
}

// Round 6
// 96.369 us; speedup vs baseline: 1.8134x; 1.8134x over previous
//
#include <hip/hip_runtime.h>

#define BB 4
#define CC 3
#define HH 512
#define WW 512
#define NS 81              // 9 x 9 shifts
#define IMG (HH * WW)
#define CHW (CC * IMG)
#define STRIP 8            // rows per k_sims block
#define NSTRIPS (HH / STRIP)             // 64
#define NBLK (BB * CC * NSTRIPS)         // 768 blocks = EXACTLY 3 per CU
#define SLOTS (CC * NSTRIPS)             // 192 partials per (b, sim)

// R17: occupancy is the whole story. R16's counters: VGPR=32, Occupancy
// 26.6% = exactly ONE 9-wave block/CU (384-block grid -> 128-block tail at
// half-chip). The m69 ladder: 9-wave blocks need VGPR<=64 for 3 blocks/CU
// (27 waves); VGPR 65..128 -> 16-wave ceiling -> 1 block. R14/R15's
// launch_bounds(576,4) capped at 128 -> still 1 block -> inner-loop changes
// nulled. And the 256MiB poison fill evicts L2+L3 every iteration (FETCH
// 15.5MB/iter) -> loads are ~900cyc cold-HBM stalls that 2.25 waves/SIMD
// can't hide. Fix: 768 blocks (3/CU, no tail) + launch_bounds(576,8)
// (VGPR<=64; compiler naturally at 32) + R13's proven shuffle-halo body.
// No fences, no last-block tail (R16's L2-writeback storm: never again).
__device__ double g_part[(size_t)BB * NS * SLOTS];   // 497 KB, fully rewritten each launch
__device__ int    g_best[BB];

// constant-index component select (folds after full unroll)
#define C4(v, i) ((i) == 0 ? (v).x : (i) == 1 ? (v).y : (i) == 2 ? (v).z : (v).w)

// sim(b,sx,sy) = sum over c,i,j (both (i,j) and (i+sx,j+sy) in bounds) of
//               x[b,c,i,j] * x_ref[b,c,i+sx,j+sy]
__global__ __launch_bounds__(576, 8) void k_sims(const float* __restrict__ xref,
                                                 const float* __restrict__ x) {
    // XCD-contiguous swizzle (bijective: 768 % 8 == 0): adjacent strips share
    // halo rows; with caches cold every iteration, keep them on one XCD's L2.
    int raw   = blockIdx.x;
    int bid   = (raw & 7) * (NBLK / 8) + (raw >> 3);
    int strip = bid % NSTRIPS;
    int bc    = bid / NSTRIPS;
    int b     = bc / CC;
    const float* xp = x    + (size_t)bc * IMG;
    const float* rp = xref + (size_t)bc * IMG;
    int tid  = threadIdx.x;
    int lane = tid & 63;
    int sxi  = tid >> 6;                 // wave index == sx index (9 waves)
    int j0   = lane << 3;                // 8 floats per lane
    int sx   = sxi - 4;
    int ip0  = strip * STRIP;

    float acc[9];
#pragma unroll
    for (int s = 0; s < 9; ++s) acc[s] = 0.f;

#pragma unroll
    for (int rr = 0; rr < STRIP; ++rr) {
        int ip = ip0 + rr;               // x row (always in bounds)
        int ii = ip + sx;                // ref row (wave-uniform test)
        if ((unsigned)ii >= HH) continue;

        const float* xrow = xp + ip * WW + j0;
        const float* rrow = rp + ii * WW + j0;
        float4 xa = *(const float4*)(xrow);        // x   cols j0   .. j0+3
        float4 xb = *(const float4*)(xrow + 4);    // x   cols j0+4 .. j0+7
        float4 ra = *(const float4*)(rrow);        // ref cols j0   .. j0+3
        float4 rb = *(const float4*)(rrow + 4);    // ref cols j0+4 .. j0+7

        // halo: prev4 = ref cols j0-4..j0-1 (lane-1's rb), next4 = j0+8..j0+11
        float p0 = __shfl_up(rb.x, 1, 64);
        float p1 = __shfl_up(rb.y, 1, 64);
        float p2 = __shfl_up(rb.z, 1, 64);
        float p3 = __shfl_up(rb.w, 1, 64);
        if (lane == 0) { p0 = p1 = p2 = p3 = 0.f; }   // cols < 0 -> mask
        float n0 = __shfl_down(ra.x, 1, 64);
        float n1 = __shfl_down(ra.y, 1, 64);
        float n2 = __shfl_down(ra.z, 1, 64);
        float n3 = __shfl_down(ra.w, 1, 64);
        if (lane == 63) { n0 = n1 = n2 = n3 = 0.f; }  // cols >= 512 -> mask

#define P4(i) ((i) == 0 ? p0 : (i) == 1 ? p1 : (i) == 2 ? p2 : p3)
#define N4(i) ((i) == 0 ? n0 : (i) == 1 ? n1 : (i) == 2 ? n2 : n3)
#pragma unroll
        for (int syi = 0; syi < 9; ++syi) {
#pragma unroll
            for (int k = 0; k < 8; ++k) {
                int i = k + syi;         // window index 0..15 (constant)
                float wv = (i < 4)  ? P4(i)
                         : (i < 8)  ? C4(ra, i - 4)
                         : (i < 12) ? C4(rb, i - 8)
                         :            N4(i - 12);
                float xv = (k < 4) ? C4(xa, k) : C4(xb, k - 4);
                acc[syi] += xv * wv;
            }
        }
#undef P4
#undef N4
    }

    // Each wave owns 9 disjoint sims (its sx) -> no LDS combine, no atomics.
    // Wave shuffle-reduce (fp32), lane 0 stores fp64 partial (plain store;
    // k_reduce is a separate dispatch -> ordinary launch-edge visibility).
    int cs = (bc % CC) * NSTRIPS + strip;            // partial slot 0..191
#pragma unroll
    for (int s = 0; s < 9; ++s) {
        float v = acc[s];
        for (int off = 32; off; off >>= 1) v += __shfl_down(v, off, 64);
        if (lane == 0)
            g_part[((size_t)b * NS + sxi * 9 + s) * SLOTS + cs] = (double)v;
    }
}

// Tiny reduce: one block per batch; thread t sums its sim's 192 consecutive
// fp64 partials (fixed even/odd 2-way order -> deterministic, R14/R15-proven),
// then first-index argmax (matches jnp.argmax), writes g_best + shift tail.
__global__ __launch_bounds__(128) void k_reduce(float* __restrict__ outTail) {
    int b = blockIdx.x;
    int t = threadIdx.x;
    __shared__ double vals[NS];
    if (t < NS) {
        const double* p = g_part + ((size_t)b * NS + t) * SLOTS;
        double s0 = 0.0, s1 = 0.0;
        for (int i = 0; i < SLOTS; i += 2) { s0 += p[i]; s1 += p[i + 1]; }
        vals[t] = s0 + s1;
    }
    __syncthreads();
    if (t == 0) {
        int best = 0;
        double bv = vals[0];
        for (int i = 1; i < NS; ++i)
            if (vals[i] > bv) { bv = vals[i]; best = i; }   // strict >: first index wins
        g_best[b] = best;
        outTail[b * 2]     = (float)(best / 9 - 4);
        outTail[b * 2 + 1] = (float)(best % 9 - 4);
    }
}

// Pure shift-copy: reads precomputed g_best[b] (wave-uniform scalar load).
// Copy body unchanged from R11-R16 (proven exact).
__global__ __launch_bounds__(256) void k_apply(const float* __restrict__ x,
                                               float* __restrict__ out) {
    int blk = blockIdx.x;
    int bc  = blk >> 8;                 // 256 blocks per image (512 rows / 2)
    int tid = threadIdx.x;
    int b   = bc / CC;

    int bi = g_best[b];
    int sx = bi / 9 - 4;
    int sy = bi % 9 - 4;

    int row = ((blk & 255) << 1) + (tid >> 7);
    int j0  = (tid & 127) << 2;
    int is  = row - sx;
    float4 v = make_float4(0.f, 0.f, 0.f, 0.f);
    if ((unsigned)is < HH) {
        const float* src = x + (size_t)bc * IMG + is * WW;
        int js0 = j0 - sy;
        if (js0 >= 0 && js0 + 3 < WW) {
            v = *(const float4*)(src + js0);   // 4B-aligned dwordx4, exact (R2-R17)
        } else {
            float* vv = (float*)&v;
#pragma unroll
            for (int k = 0; k < 4; ++k) {
                int js = js0 + k;
                if ((unsigned)js < WW) vv[k] = src[js];
            }
        }
    }
    *(float4*)(out + (size_t)bc * IMG + row * WW + j0) = v;
}

extern "C" void kernel_launch(void* const* d_in, const int* in_sizes, int n_in,
                              void* d_out, int out_size, void* d_ws, size_t ws_size,
                              hipStream_t stream) {
    const float* xref = (const float*)d_in[0];
    const float* x    = (const float*)d_in[1];
    float* out = (float*)d_out;
    (void)d_ws; (void)ws_size;          // workspace unused (poison fill is unconditional)

    k_sims<<<NBLK, 576, 0, stream>>>(xref, x);
    k_reduce<<<BB, 128, 0, stream>>>(out + (size_t)BB * CHW);

    int applyBlocks = (BB * CC * HH) / 2;   // 3072
    k_apply<<<applyBlocks, 256, 0, stream>>>(x, out);
}